// Round 11
// baseline (766.616 us; speedup 1.0000x reference)
//
#include <hip/hip_runtime.h>
#include <hip/hip_bf16.h>

#define B_ 16
#define S_ 80
#define D_ 512
#define H_ 64
#define DI_ 2048
#define L_ 6
#define G4H 256            // 4*H
#define NROW (B_ * S_)     // 1280 rows = (b, s)
#define EPS_ 1e-6f

typedef __attribute__((ext_vector_type(8))) short short8;
typedef __attribute__((ext_vector_type(4))) float f32x4;

// ---------------- math helpers ----------------
__device__ __forceinline__ float sigmoidf_(float x) {
    return __fdividef(1.0f, 1.0f + __expf(-x));
}
__device__ __forceinline__ float tanh_(float x) {
    return __fdividef(2.0f, 1.0f + __expf(-2.0f * x)) - 1.0f;
}
__device__ __forceinline__ short f2bf(float f) {
    __hip_bfloat16 h = __float2bfloat16(f);   // RNE
    return *reinterpret_cast<short*>(&h);
}

// Barrier that waits only on LDS traffic (lgkmcnt), NOT on in-flight global loads.
__device__ __forceinline__ void lds_barrier() {
    __asm__ volatile("s_waitcnt lgkmcnt(0)\n\ts_barrier" ::: "memory");
}

// ---------------- fp32 -> bf16 weight conversion: ALL weights, ONE launch ----------------
__global__ __launch_bounds__(256)
void w2bf_all_kernel(const float* __restrict__ s0, int n0, __hip_bfloat16* __restrict__ d0,
                     const float* __restrict__ s1, int n1, __hip_bfloat16* __restrict__ d1,
                     const float* __restrict__ s2, int n2, __hip_bfloat16* __restrict__ d2,
                     const float* __restrict__ s3, int n3, __hip_bfloat16* __restrict__ d3) {
    int i = blockIdx.x * 256 + threadIdx.x;
    const float* s; __hip_bfloat16* d;
    if (i < n0)      { s = s0; d = d0; }
    else if ((i -= n0) < n1) { s = s1; d = d1; }
    else if ((i -= n1) < n2) { s = s2; d = d2; }
    else if ((i -= n2) < n3) { s = s3; d = d3; }
    else return;
    float4 v = reinterpret_cast<const float4*>(s)[i];
    short4 o;
    o.x = f2bf(v.x); o.y = f2bf(v.y); o.z = f2bf(v.z); o.w = f2bf(v.w);
    reinterpret_cast<short4*>(d)[i] = o;
}

// ---------------- LayerNorm: one block per row, shuffle reduce (2 barriers) ----------------
__global__ __launch_bounds__(256)
void ln_kernel(const float* __restrict__ x, const float* __restrict__ g,
               const float* __restrict__ b, __hip_bfloat16* __restrict__ out) {
    int row = blockIdx.x;
    int t = threadIdx.x;
    const float* xr = x + (size_t)row * D_;
    float v0 = xr[t], v1 = xr[t + 256];
    __shared__ float ws4[4], qs4[4];
    float s = v0 + v1;
    #pragma unroll
    for (int o = 32; o > 0; o >>= 1) s += __shfl_down(s, o);
    if ((t & 63) == 0) ws4[t >> 6] = s;
    __syncthreads();
    float m = (ws4[0] + ws4[1] + ws4[2] + ws4[3]) * (1.0f / (float)D_);
    float d0 = v0 - m, d1 = v1 - m;
    float q = d0 * d0 + d1 * d1;
    #pragma unroll
    for (int o = 32; o > 0; o >>= 1) q += __shfl_down(q, o);
    if ((t & 63) == 0) qs4[t >> 6] = q;
    __syncthreads();
    float rs = rsqrtf((qs4[0] + qs4[1] + qs4[2] + qs4[3]) * (1.0f / (float)D_) + EPS_);
    __hip_bfloat16* orow = out + (size_t)row * D_;
    orow[t]       = __float2bfloat16(d0 * rs * g[t]       + b[t]);
    orow[t + 256] = __float2bfloat16(d1 * rs * g[t + 256] + b[t + 256]);
}

// ---------------- bf16 MFMA GEMM (64x64 tile): C = A @ W^T (+bias)(+relu)(+res) ----------
// OUT_MODE: 0 = fp32 row-major, 1 = bf16 row-major,
//           2 = fp32 xg5 layout [s][half][gate][unit64][slot8]  (half=b>>3, slot=b&7)
template<int WITH_BIAS, int WITH_RELU, int WITH_RES, int OUT_MODE>
__global__ __launch_bounds__(256)
void mfma_gemm(const __hip_bfloat16* __restrict__ A, const __hip_bfloat16* __restrict__ W,
               const float* __restrict__ bias, const float* __restrict__ res,
               void* __restrict__ C, int M, int N, int K) {
    const int LDT = 72;  // LDS row stride in shorts (144B rows, 16B-aligned)
    __shared__ short As[64 * LDT];
    __shared__ short Ws[64 * LDT];

    int tid  = threadIdx.x;
    int wave = tid >> 6, lane = tid & 63;
    int quad = lane >> 4, l16 = lane & 15;
    int m_off = (wave >> 1) * 32, n_off = (wave & 1) * 32;
    int m0 = blockIdx.y * 64, n0 = blockIdx.x * 64;

    int r = tid >> 2, c = tid & 3;           // staging: row 0..63, 16-elem chunk 0..3
    const short* Ag = reinterpret_cast<const short*>(A);
    const short* Wg = reinterpret_cast<const short*>(W);

    f32x4 acc00 = {0.f,0.f,0.f,0.f}, acc01 = acc00, acc10 = acc00, acc11 = acc00;

    short8 avA[2], avW[2];                   // staged tile in registers
    auto load_tile = [&](int k0) {
        const short* arow = &Ag[(size_t)(m0 + r) * K + k0 + c * 16];
        avA[0] = *reinterpret_cast<const short8*>(arow);
        avA[1] = *reinterpret_cast<const short8*>(arow + 8);
        const short* wrow = &Wg[(size_t)(n0 + r) * K + k0 + c * 16];
        avW[0] = *reinterpret_cast<const short8*>(wrow);
        avW[1] = *reinterpret_cast<const short8*>(wrow + 8);
    };

    load_tile(0);                            // prologue
    for (int k0 = 0; k0 < K; k0 += 64) {
        lds_barrier();                       // prev frag reads done; vmem stays in flight
        *reinterpret_cast<short8*>(&As[r * LDT + c * 16])     = avA[0];
        *reinterpret_cast<short8*>(&As[r * LDT + c * 16 + 8]) = avA[1];
        *reinterpret_cast<short8*>(&Ws[r * LDT + c * 16])     = avW[0];
        *reinterpret_cast<short8*>(&Ws[r * LDT + c * 16 + 8]) = avW[1];
        lds_barrier();
        if (k0 + 64 < K) load_tile(k0 + 64); // issue next loads; consumed next iteration

        #pragma unroll
        for (int kc = 0; kc < 2; kc++) {
            short8 a0 = *reinterpret_cast<const short8*>(&As[(m_off + l16) * LDT + kc * 32 + quad * 8]);
            short8 a1 = *reinterpret_cast<const short8*>(&As[(m_off + 16 + l16) * LDT + kc * 32 + quad * 8]);
            short8 b0 = *reinterpret_cast<const short8*>(&Ws[(n_off + l16) * LDT + kc * 32 + quad * 8]);
            short8 b1 = *reinterpret_cast<const short8*>(&Ws[(n_off + 16 + l16) * LDT + kc * 32 + quad * 8]);
            acc00 = __builtin_amdgcn_mfma_f32_16x16x32_bf16(a0, b0, acc00, 0, 0, 0);
            acc01 = __builtin_amdgcn_mfma_f32_16x16x32_bf16(a0, b1, acc01, 0, 0, 0);
            acc10 = __builtin_amdgcn_mfma_f32_16x16x32_bf16(a1, b0, acc10, 0, 0, 0);
            acc11 = __builtin_amdgcn_mfma_f32_16x16x32_bf16(a1, b1, acc11, 0, 0, 0);
        }
    }

    f32x4 accs[2][2] = {{acc00, acc01}, {acc10, acc11}};
    #pragma unroll
    for (int fi = 0; fi < 2; fi++) {
        #pragma unroll
        for (int fj = 0; fj < 2; fj++) {
            int coln = n0 + n_off + fj * 16 + l16;
            float bv = WITH_BIAS ? bias[coln] : 0.0f;
            #pragma unroll
            for (int rr = 0; rr < 4; rr++) {
                int rowm = m0 + m_off + fi * 16 + quad * 4 + rr;
                float v = accs[fi][fj][rr];
                if (WITH_BIAS) v += bv;
                if (WITH_RELU) v = fmaxf(v, 0.0f);
                if (WITH_RES)  v += res[(size_t)rowm * N + coln];
                if (OUT_MODE == 0) {
                    reinterpret_cast<float*>(C)[(size_t)rowm * N + coln] = v;
                } else if (OUT_MODE == 1) {
                    reinterpret_cast<__hip_bfloat16*>(C)[(size_t)rowm * N + coln] = __float2bfloat16(v);
                } else {
                    int b_ = rowm / S_;
                    int s_ = rowm - b_ * S_;
                    int gate = coln >> 6, u = coln & 63;
                    int half = b_ >> 3, slot = b_ & 7;
                    reinterpret_cast<float*>(C)[
                        ((((size_t)(s_ * 2 + half) * 4 + gate) * 64 + u) << 3) + slot] = v;
                }
            }
        }
    }
}

// ---------------- MFMA LSTM + fused FC(+res) + LN2, v15: flag-sync instead of s_barrier ----
// Recurrence layout = proven v13 (58us). ONE isolated change: the per-step
// lds_barrier is replaced by monotone LDS flag sync. Wave w, after its h writes
// land (lgkmcnt(0)), publishes hflag[w]=t+1; at step t+1 each wave spins on a
// broadcast ds_read of the 4 flags before reading h. A wave passes the spin only
// when all waves COMPLETED step t (writes follow reads), so the parity buffer it
// overwrites has been fully read -- 2-buffer rotation stays safe. Flags are
// monotone -> no deadlock. Tests whether the s_barrier rendezvous is the dominant
// share of the 1650cy step (v8's wave-count null is consistent with that).
__global__ __launch_bounds__(256)
void lstm_fc_kernel(const float* __restrict__ xg5,   // [S][2][4][64][8] fp32
                    const float* __restrict__ whh,   // [4H, H] fp32 (layer slice)
                    const __hip_bfloat16* __restrict__ wfcb,  // [D, H] bf16 (layer slice)
                    const float* __restrict__ g2,    // ln2 gamma [D]
                    const float* __restrict__ b2v,   // ln2 beta  [D]
                    float* __restrict__ xcur,        // [NROW, D] fp32, in/out (residual)
                    __hip_bfloat16* __restrict__ lnb) { // [NROW, D] bf16 LN2 output
    const int i    = blockIdx.x;      // output position 0..79
    const int bh   = blockIdx.y;      // batch half 0..1
    const int tid  = threadIdx.x;
    const int wave = tid >> 6, lane = tid & 63;
    const int quad = lane >> 4, l16 = lane & 15;
    const int unit = wave * 16 + l16; // hidden unit owned on the C side

    short8 bfrag[4][2];
    #pragma unroll
    for (int g = 0; g < 4; g++) {
        const float* wr = &whh[(size_t)(g * 64 + unit) * H_];
        #pragma unroll
        for (int kc = 0; kc < 2; kc++) {
            float4 x0 = *(const float4*)(wr + kc * 32 + quad * 8);
            float4 x1 = *(const float4*)(wr + kc * 32 + quad * 8 + 4);
            short8 v;
            v[0] = f2bf(x0.x); v[1] = f2bf(x0.y); v[2] = f2bf(x0.z); v[3] = f2bf(x0.w);
            v[4] = f2bf(x1.x); v[5] = f2bf(x1.y); v[6] = f2bf(x1.z); v[7] = f2bf(x1.w);
            bfrag[g][kc] = v;
        }
    }

    __shared__ __attribute__((aligned(16))) short hsh[2][16][72];
    __shared__ float sred[4][4][2][2];    // [wave][quad][state][{sum,sumsq}]
    __shared__ int hflagv[4];             // per-wave completed-step counters
    for (int idx = tid; idx < 2 * 16 * 72; idx += 256)
        reinterpret_cast<short*>(hsh)[idx] = 0;
    if (tid < 4) hflagv[tid] = 0;

    float cst[2] = {0.f, 0.f};

    size_t xoff[4];
    #pragma unroll
    for (int g = 0; g < 4; g++)
        xoff[g] = ((((size_t)bh * 4 + g) * 64 + unit) << 3) + quad * 2;

    auto xload = [&](float2 (&xv)[4], int t) {
        int s = (t == i) ? (S_ - 1) : ((t == S_ - 1) ? i : t);   // janossy permutation
        const float* base = xg5 + (size_t)s * 4096;
        #pragma unroll
        for (int g = 0; g < 4; g++)
            xv[g] = *reinterpret_cast<const float2*>(base + xoff[g]);
    };

    float2 xvA[4], xvB[4];
    xload(xvA, 0);
    xload(xvB, 1);

    lds_barrier();  // LDS zero-init + flag init visible

    const f32x4 zacc = {0.f, 0.f, 0.f, 0.f};

    auto stepv = [&](int t, float2 (&xc)[4]) {
        const int pb = t & 1;
        // ---- flag spin: all waves completed step t-1 (their h writes landed) ----
        if (t > 0) {
            volatile int* vf = hflagv;
            int f0, f1, f2, f3;
            do { f0 = vf[0]; f1 = vf[1]; f2 = vf[2]; f3 = vf[3]; }
            while (f0 < t || f1 < t || f2 < t || f3 < t);
            __asm__ volatile("" ::: "memory");   // fence compiler: h reads stay below
        }
        short8 af0 = *reinterpret_cast<const short8*>(&hsh[pb][l16][quad * 8]);
        short8 af1 = *reinterpret_cast<const short8*>(&hsh[pb][l16][32 + quad * 8]);

        f32x4 p0 = __builtin_amdgcn_mfma_f32_16x16x32_bf16(af0, bfrag[0][0], zacc, 0, 0, 0);
        f32x4 q0 = __builtin_amdgcn_mfma_f32_16x16x32_bf16(af1, bfrag[0][1], zacc, 0, 0, 0);
        f32x4 p1 = __builtin_amdgcn_mfma_f32_16x16x32_bf16(af0, bfrag[1][0], zacc, 0, 0, 0);
        f32x4 q1 = __builtin_amdgcn_mfma_f32_16x16x32_bf16(af1, bfrag[1][1], zacc, 0, 0, 0);
        f32x4 p2 = __builtin_amdgcn_mfma_f32_16x16x32_bf16(af0, bfrag[2][0], zacc, 0, 0, 0);
        f32x4 q2 = __builtin_amdgcn_mfma_f32_16x16x32_bf16(af1, bfrag[2][1], zacc, 0, 0, 0);
        f32x4 p3 = __builtin_amdgcn_mfma_f32_16x16x32_bf16(af0, bfrag[3][0], zacc, 0, 0, 0);
        f32x4 q3 = __builtin_amdgcn_mfma_f32_16x16x32_bf16(af1, bfrag[3][1], zacc, 0, 0, 0);

        float gi0 = p0[0] + q0[0] + xc[0].x, gi1 = p0[1] + q0[1] + xc[0].y;
        float gf0 = p1[0] + q1[0] + xc[1].x, gf1 = p1[1] + q1[1] + xc[1].y;
        float gg0 = p2[0] + q2[0] + xc[2].x, gg1 = p2[1] + q2[1] + xc[2].y;
        float go0 = p3[0] + q3[0] + xc[3].x, go1 = p3[1] + q3[1] + xc[3].y;

        if (t + 2 < S_) xload(xc, t + 2);

        {
            float ig = sigmoidf_(gi0);
            float fg = sigmoidf_(gf0);
            float gv = tanh_(gg0);
            float og = sigmoidf_(go0);
            float cc = fg * cst[0] + ig * gv;
            cst[0] = cc;
            hsh[pb ^ 1][quad * 4 + 0][unit] = f2bf(og * tanh_(cc));
        }
        {
            float ig = sigmoidf_(gi1);
            float fg = sigmoidf_(gf1);
            float gv = tanh_(gg1);
            float og = sigmoidf_(go1);
            float cc = fg * cst[1] + ig * gv;
            cst[1] = cc;
            hsh[pb ^ 1][quad * 4 + 1][unit] = f2bf(og * tanh_(cc));
        }
        // publish: this wave's step-t writes have landed
        __asm__ volatile("s_waitcnt lgkmcnt(0)" ::: "memory");
        if (lane == 0) *(volatile int*)&hflagv[wave] = t + 1;
    };

    for (int t = 0; t < S_; t += 2) { stepv(t, xvA); stepv(t + 1, xvB); }

    lds_barrier();   // all waves' final h (step 79 -> hsh[0]) visible for the epilogue

    // ---- fused FC (+residual) + LN2 epilogue (unchanged from v13) ----
    {
        const short* wf = reinterpret_cast<const short*>(wfcb);
        short8 af0 = *reinterpret_cast<const short8*>(&hsh[0][l16][quad * 8]);
        short8 af1 = *reinterpret_cast<const short8*>(&hsh[0][l16][32 + quad * 8]);

        f32x4 facc[8];
        #pragma unroll
        for (int nn = 0; nn < 8; nn++) {
            int col16 = (wave * 8 + nn) * 16 + l16;
            short8 w0 = *reinterpret_cast<const short8*>(&wf[(size_t)col16 * H_ + quad * 8]);
            short8 w1 = *reinterpret_cast<const short8*>(&wf[(size_t)col16 * H_ + 32 + quad * 8]);
            f32x4 a = __builtin_amdgcn_mfma_f32_16x16x32_bf16(af0, w0, zacc, 0, 0, 0);
            facc[nn] = __builtin_amdgcn_mfma_f32_16x16x32_bf16(af1, w1, a, 0, 0, 0);
        }

        float xn[8][2];
        float ssum[2] = {0.f, 0.f}, sq[2] = {0.f, 0.f};
        #pragma unroll
        for (int nn = 0; nn < 8; nn++) {
            int col = (wave * 8 + nn) * 16 + l16;
            #pragma unroll
            for (int rr = 0; rr < 2; rr++) {
                int b = bh * 8 + quad * 2 + rr;
                size_t adr = ((size_t)b * S_ + i) * D_ + col;
                float v = facc[nn][rr] + xcur[adr];
                xn[nn][rr] = v;
                xcur[adr] = v;
                ssum[rr] += v;
                sq[rr]   += v * v;
            }
        }
        #pragma unroll
        for (int m = 1; m < 16; m <<= 1) {
            ssum[0] += __shfl_xor(ssum[0], m); ssum[1] += __shfl_xor(ssum[1], m);
            sq[0]   += __shfl_xor(sq[0], m);   sq[1]   += __shfl_xor(sq[1], m);
        }
        if (l16 == 0) {
            #pragma unroll
            for (int rr = 0; rr < 2; rr++) {
                sred[wave][quad][rr][0] = ssum[rr];
                sred[wave][quad][rr][1] = sq[rr];
            }
        }
        lds_barrier();
        float mmean[2], rstd[2];
        #pragma unroll
        for (int rr = 0; rr < 2; rr++) {
            float s = sred[0][quad][rr][0] + sred[1][quad][rr][0]
                    + sred[2][quad][rr][0] + sred[3][quad][rr][0];
            float q = sred[0][quad][rr][1] + sred[1][quad][rr][1]
                    + sred[2][quad][rr][1] + sred[3][quad][rr][1];
            float m = s * (1.0f / (float)D_);
            mmean[rr] = m;
            rstd[rr]  = rsqrtf(q * (1.0f / (float)D_) - m * m + EPS_);
        }
        #pragma unroll
        for (int nn = 0; nn < 8; nn++) {
            int col = (wave * 8 + nn) * 16 + l16;
            float gv = g2[col], bv = b2v[col];
            #pragma unroll
            for (int rr = 0; rr < 2; rr++) {
                int b = bh * 8 + quad * 2 + rr;
                lnb[((size_t)b * S_ + i) * D_ + col] =
                    __float2bfloat16((xn[nn][rr] - mmean[rr]) * rstd[rr] * gv + bv);
            }
        }
    }
}

// ---------------- final LN + projection to one logit per row ----------------
__global__ __launch_bounds__(256)
void final_kernel(const float* __restrict__ x, const float* __restrict__ g,
                  const float* __restrict__ b, const float* __restrict__ wprj,
                  float* __restrict__ out) {
    int row = blockIdx.x;
    int t = threadIdx.x;
    const float* xr = x + (size_t)row * D_;
    float v0 = xr[t], v1 = xr[t + 256];
    __shared__ float red[256];
    red[t] = v0 + v1;
    __syncthreads();
    for (int o = 128; o > 0; o >>= 1) { if (t < o) red[t] += red[t + o]; __syncthreads(); }
    float m = red[0] * (1.0f / (float)D_);
    __syncthreads();
    float d0 = v0 - m, d1 = v1 - m;
    red[t] = d0 * d0 + d1 * d1;
    __syncthreads();
    for (int o = 128; o > 0; o >>= 1) { if (t < o) red[t] += red[t + o]; __syncthreads(); }
    float rs = rsqrtf(red[0] * (1.0f / (float)D_) + EPS_);
    __syncthreads();
    float y0 = (d0 * rs * g[t] + b[t]) * wprj[t];
    float y1 = (d1 * rs * g[t + 256] + b[t + 256]) * wprj[t + 256];
    red[t] = y0 + y1;
    __syncthreads();
    for (int o = 128; o > 0; o >>= 1) { if (t < o) red[t] += red[t + o]; __syncthreads(); }
    if (t == 0) out[row] = red[0];
}

// ---------------- host ----------------
extern "C" void kernel_launch(void* const* d_in, const int* in_sizes, int n_in,
                              void* d_out, int out_size, void* d_ws, size_t ws_size,
                              hipStream_t stream) {
    const float* src   = (const float*)d_in[0];
    const float* ln1_g = (const float*)d_in[2];
    const float* ln1_b = (const float*)d_in[3];
    const float* wih   = (const float*)d_in[4];   // [L, 4H, D]
    const float* whh   = (const float*)d_in[5];   // [L, 4H, H]
    const float* wfc   = (const float*)d_in[6];   // [L, D, H]
    const float* ln2_g = (const float*)d_in[7];
    const float* ln2_b = (const float*)d_in[8];
    const float* w1    = (const float*)d_in[9];   // [L, DI, D]
    const float* b1    = (const float*)d_in[10];  // [L, DI]
    const float* w2    = (const float*)d_in[11];  // [L, D, DI]
    const float* b2    = (const float*)d_in[12];  // [L, D]
    const float* lnf_g = (const float*)d_in[13];
    const float* lnf_b = (const float*)d_in[14];
    const float* wprj  = (const float*)d_in[15];  // [1, D]
    float* out = (float*)d_out;

    char* ws = (char*)d_ws;
    float* xcur = (float*)ws;                       ws += (size_t)NROW * D_  * 4;  // fp32 residual stream
    __hip_bfloat16* lnb = (__hip_bfloat16*)ws;      ws += (size_t)NROW * D_  * 2;  // LN output (bf16 A-operand)
    float* xg5  = (float*)ws;                       ws += (size_t)S_ * 4096  * 4;  // gate proj fp32 [s][2][4][64][8]
    __hip_bfloat16* f1  = (__hip_bfloat16*)ws;      ws += (size_t)NROW * DI_ * 2;  // FFN hidden (bf16 A-operand)
    __hip_bfloat16* wihb = (__hip_bfloat16*)ws;     ws += (size_t)L_ * G4H * D_ * 2;
    __hip_bfloat16* wfcb = (__hip_bfloat16*)ws;     ws += (size_t)L_ * D_ * H_ * 2;
    __hip_bfloat16* w1b  = (__hip_bfloat16*)ws;     ws += (size_t)L_ * DI_ * D_ * 2;
    __hip_bfloat16* w2b  = (__hip_bfloat16*)ws;     ws += (size_t)L_ * D_ * DI_ * 2;

    // one-time (per launch) weight conversions to bf16 -- single dispatch
    {
        int n0 = L_ * G4H * D_ / 4;   // wih
        int n1 = L_ * D_ * H_ / 4;    // wfc
        int n2 = L_ * DI_ * D_ / 4;   // w1
        int n3 = L_ * D_ * DI_ / 4;   // w2
        int total = n0 + n1 + n2 + n3;
        w2bf_all_kernel<<<(total + 255) / 256, 256, 0, stream>>>(
            wih, n0, wihb, wfc, n1, wfcb, w1, n2, w1b, w2, n3, w2b);
    }

    hipMemcpyAsync(xcur, src, (size_t)NROW * D_ * sizeof(float),
                   hipMemcpyDeviceToDevice, stream);

    for (int l = 0; l < L_; l++) {
        // --- janossy layer: ln1 -> xg-gemm -> lstm(+fc+res+ln2) ---
        ln_kernel<<<NROW, 256, 0, stream>>>(xcur, ln1_g + (size_t)l * D_,
                                            ln1_b + (size_t)l * D_, lnb);
        mfma_gemm<0, 0, 0, 2><<<dim3(G4H / 64, NROW / 64), 256, 0, stream>>>(
            lnb, wihb + (size_t)l * G4H * D_, nullptr, nullptr, xg5, NROW, G4H, D_);
        lstm_fc_kernel<<<dim3(S_, 2), 256, 0, stream>>>(
            xg5, whh + (size_t)l * G4H * H_, wfcb + (size_t)l * D_ * H_,
            ln2_g + (size_t)l * D_, ln2_b + (size_t)l * D_, xcur, lnb);
        // --- FFN: ffn1 (reads lnb from lstm epilogue) -> ffn2(+res) ---
        mfma_gemm<1, 1, 0, 1><<<dim3(DI_ / 64, NROW / 64), 256, 0, stream>>>(
            lnb, w1b + (size_t)l * DI_ * D_, b1 + (size_t)l * DI_, nullptr, f1, NROW, DI_, D_);
        mfma_gemm<1, 0, 1, 0><<<dim3(D_ / 64, NROW / 64), 256, 0, stream>>>(
            f1, w2b + (size_t)l * D_ * DI_, b2 + (size_t)l * D_, xcur, xcur, NROW, D_, DI_);
    }
    final_kernel<<<NROW, 256, 0, stream>>>(xcur, lnf_g, lnf_b, wprj, out);
}

// Round 12
// 691.988 us; speedup vs baseline: 1.1078x; 1.1078x over previous
//
#include <hip/hip_runtime.h>
#include <hip/hip_bf16.h>

#define B_ 16
#define S_ 80
#define D_ 512
#define H_ 64
#define DI_ 2048
#define L_ 6
#define G4H 256            // 4*H
#define NROW (B_ * S_)     // 1280 rows = (b, s)
#define EPS_ 1e-6f

typedef __attribute__((ext_vector_type(8))) short short8;
typedef __attribute__((ext_vector_type(4))) float f32x4;

// ---------------- math helpers ----------------
__device__ __forceinline__ float sigmoidf_(float x) {
    return __fdividef(1.0f, 1.0f + __expf(-x));
}
__device__ __forceinline__ float tanh_(float x) {
    return __fdividef(2.0f, 1.0f + __expf(-2.0f * x)) - 1.0f;
}
__device__ __forceinline__ short f2bf(float f) {
    __hip_bfloat16 h = __float2bfloat16(f);   // RNE
    return *reinterpret_cast<short*>(&h);
}

// Barrier that waits only on LDS traffic (lgkmcnt), NOT on in-flight global loads.
__device__ __forceinline__ void lds_barrier() {
    __asm__ volatile("s_waitcnt lgkmcnt(0)\n\ts_barrier" ::: "memory");
}

// ---------------- fp32 -> bf16 weight conversion: ALL weights, ONE launch ----------------
__global__ __launch_bounds__(256)
void w2bf_all_kernel(const float* __restrict__ s0, int n0, __hip_bfloat16* __restrict__ d0,
                     const float* __restrict__ s1, int n1, __hip_bfloat16* __restrict__ d1,
                     const float* __restrict__ s2, int n2, __hip_bfloat16* __restrict__ d2,
                     const float* __restrict__ s3, int n3, __hip_bfloat16* __restrict__ d3) {
    int i = blockIdx.x * 256 + threadIdx.x;
    const float* s; __hip_bfloat16* d;
    if (i < n0)      { s = s0; d = d0; }
    else if ((i -= n0) < n1) { s = s1; d = d1; }
    else if ((i -= n1) < n2) { s = s2; d = d2; }
    else if ((i -= n2) < n3) { s = s3; d = d3; }
    else return;
    float4 v = reinterpret_cast<const float4*>(s)[i];
    short4 o;
    o.x = f2bf(v.x); o.y = f2bf(v.y); o.z = f2bf(v.z); o.w = f2bf(v.w);
    reinterpret_cast<short4*>(d)[i] = o;
}

// ---------------- LayerNorm: one block per row, shuffle reduce (2 barriers) ----------------
__global__ __launch_bounds__(256)
void ln_kernel(const float* __restrict__ x, const float* __restrict__ g,
               const float* __restrict__ b, __hip_bfloat16* __restrict__ out) {
    int row = blockIdx.x;
    int t = threadIdx.x;
    const float* xr = x + (size_t)row * D_;
    float v0 = xr[t], v1 = xr[t + 256];
    __shared__ float ws4[4], qs4[4];
    float s = v0 + v1;
    #pragma unroll
    for (int o = 32; o > 0; o >>= 1) s += __shfl_down(s, o);
    if ((t & 63) == 0) ws4[t >> 6] = s;
    __syncthreads();
    float m = (ws4[0] + ws4[1] + ws4[2] + ws4[3]) * (1.0f / (float)D_);
    float d0 = v0 - m, d1 = v1 - m;
    float q = d0 * d0 + d1 * d1;
    #pragma unroll
    for (int o = 32; o > 0; o >>= 1) q += __shfl_down(q, o);
    if ((t & 63) == 0) qs4[t >> 6] = q;
    __syncthreads();
    float rs = rsqrtf((qs4[0] + qs4[1] + qs4[2] + qs4[3]) * (1.0f / (float)D_) + EPS_);
    __hip_bfloat16* orow = out + (size_t)row * D_;
    orow[t]       = __float2bfloat16(d0 * rs * g[t]       + b[t]);
    orow[t + 256] = __float2bfloat16(d1 * rs * g[t + 256] + b[t + 256]);
}

// ---------------- bf16 MFMA GEMM (64x64 tile): C = A @ W^T (+bias)(+relu)(+res) ----------
// OUT_MODE: 0 = fp32 row-major, 1 = bf16 row-major,
//           2 = fp32 xg5 layout [s][half][gate][unit64][slot8]  (half=b>>3, slot=b&7)
template<int WITH_BIAS, int WITH_RELU, int WITH_RES, int OUT_MODE>
__global__ __launch_bounds__(256)
void mfma_gemm(const __hip_bfloat16* __restrict__ A, const __hip_bfloat16* __restrict__ W,
               const float* __restrict__ bias, const float* __restrict__ res,
               void* __restrict__ C, int M, int N, int K) {
    const int LDT = 72;  // LDS row stride in shorts (144B rows, 16B-aligned)
    __shared__ short As[64 * LDT];
    __shared__ short Ws[64 * LDT];

    int tid  = threadIdx.x;
    int wave = tid >> 6, lane = tid & 63;
    int quad = lane >> 4, l16 = lane & 15;
    int m_off = (wave >> 1) * 32, n_off = (wave & 1) * 32;
    int m0 = blockIdx.y * 64, n0 = blockIdx.x * 64;

    int r = tid >> 2, c = tid & 3;           // staging: row 0..63, 16-elem chunk 0..3
    const short* Ag = reinterpret_cast<const short*>(A);
    const short* Wg = reinterpret_cast<const short*>(W);

    f32x4 acc00 = {0.f,0.f,0.f,0.f}, acc01 = acc00, acc10 = acc00, acc11 = acc00;

    short8 avA[2], avW[2];                   // staged tile in registers
    auto load_tile = [&](int k0) {
        const short* arow = &Ag[(size_t)(m0 + r) * K + k0 + c * 16];
        avA[0] = *reinterpret_cast<const short8*>(arow);
        avA[1] = *reinterpret_cast<const short8*>(arow + 8);
        const short* wrow = &Wg[(size_t)(n0 + r) * K + k0 + c * 16];
        avW[0] = *reinterpret_cast<const short8*>(wrow);
        avW[1] = *reinterpret_cast<const short8*>(wrow + 8);
    };

    load_tile(0);                            // prologue
    for (int k0 = 0; k0 < K; k0 += 64) {
        lds_barrier();                       // prev frag reads done; vmem stays in flight
        *reinterpret_cast<short8*>(&As[r * LDT + c * 16])     = avA[0];
        *reinterpret_cast<short8*>(&As[r * LDT + c * 16 + 8]) = avA[1];
        *reinterpret_cast<short8*>(&Ws[r * LDT + c * 16])     = avW[0];
        *reinterpret_cast<short8*>(&Ws[r * LDT + c * 16 + 8]) = avW[1];
        lds_barrier();
        if (k0 + 64 < K) load_tile(k0 + 64); // issue next loads; consumed next iteration

        #pragma unroll
        for (int kc = 0; kc < 2; kc++) {
            short8 a0 = *reinterpret_cast<const short8*>(&As[(m_off + l16) * LDT + kc * 32 + quad * 8]);
            short8 a1 = *reinterpret_cast<const short8*>(&As[(m_off + 16 + l16) * LDT + kc * 32 + quad * 8]);
            short8 b0 = *reinterpret_cast<const short8*>(&Ws[(n_off + l16) * LDT + kc * 32 + quad * 8]);
            short8 b1 = *reinterpret_cast<const short8*>(&Ws[(n_off + 16 + l16) * LDT + kc * 32 + quad * 8]);
            acc00 = __builtin_amdgcn_mfma_f32_16x16x32_bf16(a0, b0, acc00, 0, 0, 0);
            acc01 = __builtin_amdgcn_mfma_f32_16x16x32_bf16(a0, b1, acc01, 0, 0, 0);
            acc10 = __builtin_amdgcn_mfma_f32_16x16x32_bf16(a1, b0, acc10, 0, 0, 0);
            acc11 = __builtin_amdgcn_mfma_f32_16x16x32_bf16(a1, b1, acc11, 0, 0, 0);
        }
    }

    f32x4 accs[2][2] = {{acc00, acc01}, {acc10, acc11}};
    #pragma unroll
    for (int fi = 0; fi < 2; fi++) {
        #pragma unroll
        for (int fj = 0; fj < 2; fj++) {
            int coln = n0 + n_off + fj * 16 + l16;
            float bv = WITH_BIAS ? bias[coln] : 0.0f;
            #pragma unroll
            for (int rr = 0; rr < 4; rr++) {
                int rowm = m0 + m_off + fi * 16 + quad * 4 + rr;
                float v = accs[fi][fj][rr];
                if (WITH_BIAS) v += bv;
                if (WITH_RELU) v = fmaxf(v, 0.0f);
                if (WITH_RES)  v += res[(size_t)rowm * N + coln];
                if (OUT_MODE == 0) {
                    reinterpret_cast<float*>(C)[(size_t)rowm * N + coln] = v;
                } else if (OUT_MODE == 1) {
                    reinterpret_cast<__hip_bfloat16*>(C)[(size_t)rowm * N + coln] = __float2bfloat16(v);
                } else {
                    int b_ = rowm / S_;
                    int s_ = rowm - b_ * S_;
                    int gate = coln >> 6, u = coln & 63;
                    int half = b_ >> 3, slot = b_ & 7;
                    reinterpret_cast<float*>(C)[
                        ((((size_t)(s_ * 2 + half) * 4 + gate) * 64 + u) << 3) + slot] = v;
                }
            }
        }
    }
}

// ---------------- MFMA LSTM + fused FC(+res) + LN2 (proven v13, 58us) ----------------
// Recurrence loop is the proven v10 (55us floor) structure, untouched. After step 79,
// block (i,bh) holds COMPLETE h vectors (all 64 units) for its 8 rows in hsh[0] --
// exactly the A-fragment layout the fc GEMM needs. Epilogue, per block, zero
// redundancy: 16 MFMAs (h @ wfc^T, K=64, this wave's 128 of 512 cols), residual add,
// xcur write, cross-wave LN2 stat reduce (one small LDS exchange), lnb write.
__global__ __launch_bounds__(256)
void lstm_fc_kernel(const float* __restrict__ xg5,   // [S][2][4][64][8] fp32
                    const float* __restrict__ whh,   // [4H, H] fp32 (layer slice)
                    const __hip_bfloat16* __restrict__ wfcb,  // [D, H] bf16 (layer slice)
                    const float* __restrict__ g2,    // ln2 gamma [D]
                    const float* __restrict__ b2v,   // ln2 beta  [D]
                    float* __restrict__ xcur,        // [NROW, D] fp32, in/out (residual)
                    __hip_bfloat16* __restrict__ lnb) { // [NROW, D] bf16 LN2 output
    const int i    = blockIdx.x;      // output position 0..79
    const int bh   = blockIdx.y;      // batch half 0..1
    const int tid  = threadIdx.x;
    const int wave = tid >> 6, lane = tid & 63;
    const int quad = lane >> 4, l16 = lane & 15;
    const int unit = wave * 16 + l16; // hidden unit owned on the C side

    short8 bfrag[4][2];
    #pragma unroll
    for (int g = 0; g < 4; g++) {
        const float* wr = &whh[(size_t)(g * 64 + unit) * H_];
        #pragma unroll
        for (int kc = 0; kc < 2; kc++) {
            float4 x0 = *(const float4*)(wr + kc * 32 + quad * 8);
            float4 x1 = *(const float4*)(wr + kc * 32 + quad * 8 + 4);
            short8 v;
            v[0] = f2bf(x0.x); v[1] = f2bf(x0.y); v[2] = f2bf(x0.z); v[3] = f2bf(x0.w);
            v[4] = f2bf(x1.x); v[5] = f2bf(x1.y); v[6] = f2bf(x1.z); v[7] = f2bf(x1.w);
            bfrag[g][kc] = v;
        }
    }

    __shared__ __attribute__((aligned(16))) short hsh[2][16][72];
    __shared__ float sred[4][4][2][2];    // [wave][quad][state][{sum,sumsq}]
    for (int idx = tid; idx < 2 * 16 * 72; idx += 256)
        reinterpret_cast<short*>(hsh)[idx] = 0;

    float cst[2] = {0.f, 0.f};

    size_t xoff[4];
    #pragma unroll
    for (int g = 0; g < 4; g++)
        xoff[g] = ((((size_t)bh * 4 + g) * 64 + unit) << 3) + quad * 2;

    auto xload = [&](float2 (&xv)[4], int t) {
        int s = (t == i) ? (S_ - 1) : ((t == S_ - 1) ? i : t);   // janossy permutation
        const float* base = xg5 + (size_t)s * 4096;
        #pragma unroll
        for (int g = 0; g < 4; g++)
            xv[g] = *reinterpret_cast<const float2*>(base + xoff[g]);
    };

    float2 xvA[4], xvB[4];
    xload(xvA, 0);
    xload(xvB, 1);

    lds_barrier();  // LDS zero-init visible

    const f32x4 zacc = {0.f, 0.f, 0.f, 0.f};

    auto stepv = [&](int t, float2 (&xc)[4]) {
        const int pb = t & 1;
        short8 af0 = *reinterpret_cast<const short8*>(&hsh[pb][l16][quad * 8]);
        short8 af1 = *reinterpret_cast<const short8*>(&hsh[pb][l16][32 + quad * 8]);

        f32x4 p0 = __builtin_amdgcn_mfma_f32_16x16x32_bf16(af0, bfrag[0][0], zacc, 0, 0, 0);
        f32x4 q0 = __builtin_amdgcn_mfma_f32_16x16x32_bf16(af1, bfrag[0][1], zacc, 0, 0, 0);
        f32x4 p1 = __builtin_amdgcn_mfma_f32_16x16x32_bf16(af0, bfrag[1][0], zacc, 0, 0, 0);
        f32x4 q1 = __builtin_amdgcn_mfma_f32_16x16x32_bf16(af1, bfrag[1][1], zacc, 0, 0, 0);
        f32x4 p2 = __builtin_amdgcn_mfma_f32_16x16x32_bf16(af0, bfrag[2][0], zacc, 0, 0, 0);
        f32x4 q2 = __builtin_amdgcn_mfma_f32_16x16x32_bf16(af1, bfrag[2][1], zacc, 0, 0, 0);
        f32x4 p3 = __builtin_amdgcn_mfma_f32_16x16x32_bf16(af0, bfrag[3][0], zacc, 0, 0, 0);
        f32x4 q3 = __builtin_amdgcn_mfma_f32_16x16x32_bf16(af1, bfrag[3][1], zacc, 0, 0, 0);

        float gi0 = p0[0] + q0[0] + xc[0].x, gi1 = p0[1] + q0[1] + xc[0].y;
        float gf0 = p1[0] + q1[0] + xc[1].x, gf1 = p1[1] + q1[1] + xc[1].y;
        float gg0 = p2[0] + q2[0] + xc[2].x, gg1 = p2[1] + q2[1] + xc[2].y;
        float go0 = p3[0] + q3[0] + xc[3].x, go1 = p3[1] + q3[1] + xc[3].y;

        if (t + 2 < S_) xload(xc, t + 2);

        {
            float ig = sigmoidf_(gi0);
            float fg = sigmoidf_(gf0);
            float gv = tanh_(gg0);
            float og = sigmoidf_(go0);
            float cc = fg * cst[0] + ig * gv;
            cst[0] = cc;
            hsh[pb ^ 1][quad * 4 + 0][unit] = f2bf(og * tanh_(cc));
        }
        {
            float ig = sigmoidf_(gi1);
            float fg = sigmoidf_(gf1);
            float gv = tanh_(gg1);
            float og = sigmoidf_(go1);
            float cc = fg * cst[1] + ig * gv;
            cst[1] = cc;
            hsh[pb ^ 1][quad * 4 + 1][unit] = f2bf(og * tanh_(cc));
        }
        lds_barrier();
    };

    for (int t = 0; t < S_; t += 2) { stepv(t, xvA); stepv(t + 1, xvB); }

    // ---- fused FC (+residual) + LN2 epilogue ----
    {
        const short* wf = reinterpret_cast<const short*>(wfcb);
        short8 af0 = *reinterpret_cast<const short8*>(&hsh[0][l16][quad * 8]);
        short8 af1 = *reinterpret_cast<const short8*>(&hsh[0][l16][32 + quad * 8]);

        f32x4 facc[8];
        #pragma unroll
        for (int nn = 0; nn < 8; nn++) {
            int col16 = (wave * 8 + nn) * 16 + l16;
            short8 w0 = *reinterpret_cast<const short8*>(&wf[(size_t)col16 * H_ + quad * 8]);
            short8 w1 = *reinterpret_cast<const short8*>(&wf[(size_t)col16 * H_ + 32 + quad * 8]);
            f32x4 a = __builtin_amdgcn_mfma_f32_16x16x32_bf16(af0, w0, zacc, 0, 0, 0);
            facc[nn] = __builtin_amdgcn_mfma_f32_16x16x32_bf16(af1, w1, a, 0, 0, 0);
        }

        float xn[8][2];
        float ssum[2] = {0.f, 0.f}, sq[2] = {0.f, 0.f};
        #pragma unroll
        for (int nn = 0; nn < 8; nn++) {
            int col = (wave * 8 + nn) * 16 + l16;
            #pragma unroll
            for (int rr = 0; rr < 2; rr++) {
                int b = bh * 8 + quad * 2 + rr;
                size_t adr = ((size_t)b * S_ + i) * D_ + col;
                float v = facc[nn][rr] + xcur[adr];
                xn[nn][rr] = v;
                xcur[adr] = v;
                ssum[rr] += v;
                sq[rr]   += v * v;
            }
        }
        #pragma unroll
        for (int m = 1; m < 16; m <<= 1) {
            ssum[0] += __shfl_xor(ssum[0], m); ssum[1] += __shfl_xor(ssum[1], m);
            sq[0]   += __shfl_xor(sq[0], m);   sq[1]   += __shfl_xor(sq[1], m);
        }
        if (l16 == 0) {
            #pragma unroll
            for (int rr = 0; rr < 2; rr++) {
                sred[wave][quad][rr][0] = ssum[rr];
                sred[wave][quad][rr][1] = sq[rr];
            }
        }
        lds_barrier();
        float mmean[2], rstd[2];
        #pragma unroll
        for (int rr = 0; rr < 2; rr++) {
            float s = sred[0][quad][rr][0] + sred[1][quad][rr][0]
                    + sred[2][quad][rr][0] + sred[3][quad][rr][0];
            float q = sred[0][quad][rr][1] + sred[1][quad][rr][1]
                    + sred[2][quad][rr][1] + sred[3][quad][rr][1];
            float m = s * (1.0f / (float)D_);
            mmean[rr] = m;
            rstd[rr]  = rsqrtf(q * (1.0f / (float)D_) - m * m + EPS_);
        }
        #pragma unroll
        for (int nn = 0; nn < 8; nn++) {
            int col = (wave * 8 + nn) * 16 + l16;
            float gv = g2[col], bv = b2v[col];
            #pragma unroll
            for (int rr = 0; rr < 2; rr++) {
                int b = bh * 8 + quad * 2 + rr;
                lnb[((size_t)b * S_ + i) * D_ + col] =
                    __float2bfloat16((xn[nn][rr] - mmean[rr]) * rstd[rr] * gv + bv);
            }
        }
    }
}

// ---------------- final LN + projection to one logit per row ----------------
__global__ __launch_bounds__(256)
void final_kernel(const float* __restrict__ x, const float* __restrict__ g,
                  const float* __restrict__ b, const float* __restrict__ wprj,
                  float* __restrict__ out) {
    int row = blockIdx.x;
    int t = threadIdx.x;
    const float* xr = x + (size_t)row * D_;
    float v0 = xr[t], v1 = xr[t + 256];
    __shared__ float red[256];
    red[t] = v0 + v1;
    __syncthreads();
    for (int o = 128; o > 0; o >>= 1) { if (t < o) red[t] += red[t + o]; __syncthreads(); }
    float m = red[0] * (1.0f / (float)D_);
    __syncthreads();
    float d0 = v0 - m, d1 = v1 - m;
    red[t] = d0 * d0 + d1 * d1;
    __syncthreads();
    for (int o = 128; o > 0; o >>= 1) { if (t < o) red[t] += red[t + o]; __syncthreads(); }
    float rs = rsqrtf(red[0] * (1.0f / (float)D_) + EPS_);
    __syncthreads();
    float y0 = (d0 * rs * g[t] + b[t]) * wprj[t];
    float y1 = (d1 * rs * g[t + 256] + b[t + 256]) * wprj[t + 256];
    red[t] = y0 + y1;
    __syncthreads();
    for (int o = 128; o > 0; o >>= 1) { if (t < o) red[t] += red[t + o]; __syncthreads(); }
    if (t == 0) out[row] = red[0];
}

// ---------------- host ----------------
extern "C" void kernel_launch(void* const* d_in, const int* in_sizes, int n_in,
                              void* d_out, int out_size, void* d_ws, size_t ws_size,
                              hipStream_t stream) {
    const float* src   = (const float*)d_in[0];
    const float* ln1_g = (const float*)d_in[2];
    const float* ln1_b = (const float*)d_in[3];
    const float* wih   = (const float*)d_in[4];   // [L, 4H, D]
    const float* whh   = (const float*)d_in[5];   // [L, 4H, H]
    const float* wfc   = (const float*)d_in[6];   // [L, D, H]
    const float* ln2_g = (const float*)d_in[7];
    const float* ln2_b = (const float*)d_in[8];
    const float* w1    = (const float*)d_in[9];   // [L, DI, D]
    const float* b1    = (const float*)d_in[10];  // [L, DI]
    const float* w2    = (const float*)d_in[11];  // [L, D, DI]
    const float* b2    = (const float*)d_in[12];  // [L, D]
    const float* lnf_g = (const float*)d_in[13];
    const float* lnf_b = (const float*)d_in[14];
    const float* wprj  = (const float*)d_in[15];  // [1, D]
    float* out = (float*)d_out;

    char* ws = (char*)d_ws;
    float* xcur = (float*)ws;                       ws += (size_t)NROW * D_  * 4;  // fp32 residual stream
    __hip_bfloat16* lnb = (__hip_bfloat16*)ws;      ws += (size_t)NROW * D_  * 2;  // LN output (bf16 A-operand)
    float* xg5  = (float*)ws;                       ws += (size_t)S_ * 4096  * 4;  // gate proj fp32 [s][2][4][64][8]
    __hip_bfloat16* f1  = (__hip_bfloat16*)ws;      ws += (size_t)NROW * DI_ * 2;  // FFN hidden (bf16 A-operand)
    __hip_bfloat16* wihb = (__hip_bfloat16*)ws;     ws += (size_t)L_ * G4H * D_ * 2;
    __hip_bfloat16* wfcb = (__hip_bfloat16*)ws;     ws += (size_t)L_ * D_ * H_ * 2;
    __hip_bfloat16* w1b  = (__hip_bfloat16*)ws;     ws += (size_t)L_ * DI_ * D_ * 2;
    __hip_bfloat16* w2b  = (__hip_bfloat16*)ws;     ws += (size_t)L_ * D_ * DI_ * 2;

    // one-time (per launch) weight conversions to bf16 -- single dispatch
    {
        int n0 = L_ * G4H * D_ / 4;   // wih
        int n1 = L_ * D_ * H_ / 4;    // wfc
        int n2 = L_ * DI_ * D_ / 4;   // w1
        int n3 = L_ * D_ * DI_ / 4;   // w2
        int total = n0 + n1 + n2 + n3;
        w2bf_all_kernel<<<(total + 255) / 256, 256, 0, stream>>>(
            wih, n0, wihb, wfc, n1, wfcb, w1, n2, w1b, w2, n3, w2b);
    }

    hipMemcpyAsync(xcur, src, (size_t)NROW * D_ * sizeof(float),
                   hipMemcpyDeviceToDevice, stream);

    for (int l = 0; l < L_; l++) {
        // --- janossy layer: ln1 -> xg-gemm -> lstm(+fc+res+ln2) ---
        ln_kernel<<<NROW, 256, 0, stream>>>(xcur, ln1_g + (size_t)l * D_,
                                            ln1_b + (size_t)l * D_, lnb);
        mfma_gemm<0, 0, 0, 2><<<dim3(G4H / 64, NROW / 64), 256, 0, stream>>>(
            lnb, wihb + (size_t)l * G4H * D_, nullptr, nullptr, xg5, NROW, G4H, D_);
        lstm_fc_kernel<<<dim3(S_, 2), 256, 0, stream>>>(
            xg5, whh + (size_t)l * G4H * H_, wfcb + (size_t)l * D_ * H_,
            ln2_g + (size_t)l * D_, ln2_b + (size_t)l * D_, xcur, lnb);
        // --- FFN: ffn1 (reads lnb from lstm epilogue) -> ffn2(+res) ---
        mfma_gemm<1, 1, 0, 1><<<dim3(DI_ / 64, NROW / 64), 256, 0, stream>>>(
            lnb, w1b + (size_t)l * DI_ * D_, b1 + (size_t)l * DI_, nullptr, f1, NROW, DI_, D_);
        mfma_gemm<1, 0, 1, 0><<<dim3(D_ / 64, NROW / 64), 256, 0, stream>>>(
            f1, w2b + (size_t)l * D_ * DI_, b2 + (size_t)l * D_, xcur, xcur, NROW, D_, DI_);
    }
    final_kernel<<<NROW, 256, 0, stream>>>(xcur, lnf_g, lnf_b, wprj, out);
}